// Round 9
// baseline (199.722 us; speedup 1.0000x reference)
//
#include <hip/hip_runtime.h>
#include <hip/hip_bf16.h>

#define H_ 256
#define N_ 64
#define L_ 2048
#define B_ 4
#define PI_ 3.14159265358979323846

// ---------------------------------------------------------------------------
// Kernel A0: per-(h,n) weight products -> Wpre[h*64+n] = 12 floats:
//   [w00r,w00i,w01r,w01i, w10r,w10i,w11r,w11i, lam_im, lam_re^2, -lam_re, 0]
// ---------------------------------------------------------------------------
__global__ __launch_bounds__(256) void wpre_k(
    const float* __restrict__ p_ri, const float* __restrict__ q_ri,
    const float* __restrict__ lam_ri, const float* __restrict__ B_ri,
    const float* __restrict__ Ct_ri, float* __restrict__ Wpre) {
  int idx = blockIdx.x * 256 + threadIdx.x;      // h*64 + n, 16384 total
  int h = idx >> 6, n = idx & 63;
  float br  = B_ri[(h*N_+n)*2+0],  bi  = B_ri[(h*N_+n)*2+1];
  float ctr = Ct_ri[(h*N_+n)*2+0], cti = Ct_ri[(h*N_+n)*2+1];
  float pr  = p_ri[2*n+0],  pim = p_ri[2*n+1];
  float qr  = q_ri[2*n+0],  qim = q_ri[2*n+1];
  float lr  = lam_ri[2*n+0], li = lam_ri[2*n+1];
  float a0r = ctr, a0i = -cti;                   // conj(Ct)
  float a1r = qr,  a1i = -qim;                   // conj(q)
  float4* wp = (float4*)(Wpre + (size_t)idx * 12);
  wp[0] = make_float4(a0r*br - a0i*bi,  a0r*bi + a0i*br,     // w00
                      a0r*pr - a0i*pim, a0r*pim + a0i*pr);   // w01
  wp[1] = make_float4(a1r*br - a1i*bi,  a1r*bi + a1i*br,     // w10
                      a1r*pr - a1i*pim, a1r*pim + a1i*pr);   // w11
  wp[2] = make_float4(li, lr*lr, -lr, 0.f);
}

// ---------------------------------------------------------------------------
// Kernel A: at_roots[h][l], all f32, zero LDS. h uniform per block ->
// Wpre reads are scalar (SMEM) loads; ~21 VALU ops per n.
//   g = -i*(2/step)*tan(pi*l/L),  c = 1 - i*tan(pi*l/L)
// ---------------------------------------------------------------------------
__global__ __launch_bounds__(256) void cauchy_at_roots(
    const float* __restrict__ Wpre, const float* __restrict__ log_step,
    float2* __restrict__ at) {
  int h = blockIdx.x >> 3;                       // uniform: 8 blocks per h
  int l = ((blockIdx.x & 7) << 8) | threadIdx.x;

  float step = expf(log_step[h]);
  float tn   = tanf((float)(PI_ / (double)L_) * (float)l);
  float G    = (2.0f / step) * tn;               // g = -i*G
  float ci   = -tn;                              // c = 1 - i*tn

  const float4* __restrict__ wp = (const float4*)(Wpre + (size_t)h * N_ * 12);

  float k00r=0.f,k00i=0.f,k01r=0.f,k01i=0.f,k10r=0.f,k10i=0.f,k11r=0.f,k11i=0.f;
  #pragma unroll 4
  for (int n = 0; n < N_; ++n) {
    float4 w0 = wp[3*n+0];
    float4 w1 = wp[3*n+1];
    float4 cc = wp[3*n+2];                       // lam_im, lam_re^2, -lam_re
    float ddi = -G - cc.x;
    float den = fmaf(ddi, ddi, cc.y);
    float id  = __builtin_amdgcn_rcpf(den);
    float rr  = cc.z * id;                       // r = 1/(g-lam)
    float ri  = -ddi * id;
    k00r = fmaf(w0.x, rr, fmaf(-w0.y, ri, k00r));
    k00i = fmaf(w0.x, ri, fmaf( w0.y, rr, k00i));
    k01r = fmaf(w0.z, rr, fmaf(-w0.w, ri, k01r));
    k01i = fmaf(w0.z, ri, fmaf( w0.w, rr, k01i));
    k10r = fmaf(w1.x, rr, fmaf(-w1.y, ri, k10r));
    k10i = fmaf(w1.x, ri, fmaf( w1.y, rr, k10i));
    k11r = fmaf(w1.z, rr, fmaf(-w1.w, ri, k11r));
    k11i = fmaf(w1.z, ri, fmaf( w1.w, rr, k11i));
  }
  float e1r = 1.0f + k11r, e1i = k11i;
  float ide = __builtin_amdgcn_rcpf(fmaf(e1r, e1r, e1i*e1i));
  float qr_ = k01r*k10r - k01i*k10i;
  float qi_ = k01r*k10i + k01i*k10r;
  float sr  = (qr_*e1r + qi_*e1i) * ide;
  float si  = (qi_*e1r - qr_*e1i) * ide;
  float fr  = k00r - sr, fi = k00i - si;
  at[h*L_ + l] = make_float2(fr - ci*fi, fi + ci*fr);
}

// ---------------------------------------------------------------------------
// Kernel B: K[h,t] = Re( FFT_2048(at_roots[h,:])[t] ) / 2048  (512 threads)
// LDS pad-swizzle SW(x)=x+(x>>5) kills the bit-reverse / twiddle-stride
// bank conflicts (consecutive lanes hit r = multiples of 32 -> one bank).
// ---------------------------------------------------------------------------
#define SW(x) ((x) + ((x) >> 5))
__global__ __launch_bounds__(512) void fft_k(
    const float2* __restrict__ at, float* __restrict__ K) {
  __shared__ float2 data[L_ + L_/32];        // 16.9 KB
  __shared__ float2 wtab[L_/2 + L_/64];      // 8.4 KB
  int h = blockIdx.x;
  int tid = threadIdx.x;

  for (int i = tid; i < L_/2; i += 512) {
    float s, c;
    sincosf(-(float)(PI_ / 1024.0) * (float)i, &s, &c);
    wtab[SW(i)] = make_float2(c, s);
  }
  for (int i = tid; i < L_; i += 512) {
    unsigned r = __brev((unsigned)i) >> 21;
    data[SW(r)] = at[h*L_ + i];
  }
  __syncthreads();

  for (int m = 2; m <= L_; m <<= 1) {
    int half = m >> 1;
    int tstep = L_ / m;
    for (int bfly = tid; bfly < L_/2; bfly += 512) {
      int pos = bfly & (half - 1);
      int i0  = ((bfly ^ pos) << 1) + pos;
      float2 w = wtab[SW(pos * tstep)];
      float2 a = data[SW(i0)];
      float2 b = data[SW(i0 + half)];
      float trr = w.x*b.x - w.y*b.y;
      float tii = w.x*b.y + w.y*b.x;
      data[SW(i0)]        = make_float2(a.x + trr, a.y + tii);
      data[SW(i0 + half)] = make_float2(a.x - trr, a.y - tii);
    }
    __syncthreads();
  }
  for (int i = tid; i < L_; i += 512)
    K[h*L_ + i] = data[SW(i)].x * (1.0f / (float)L_);
}

// ---------------------------------------------------------------------------
// Kernel C: split-K causal conv (uniform 1024 blocks, 4 chunks each).
// S=16 sub-chunks: per ss read 4 u-b128 + 8 K-b128 for 256 FMA
// (LDS bytes/chunk cut 27% vs S=8 -> below the VALU roof).
// ---------------------------------------------------------------------------
#define HT 16
#define TT 256
#define SC 128
#define JT 16
#define USTR 132
#define KSTR 388

__device__ __forceinline__ void qmap(int p, int q, int& tile, int& c) {
  int nchA = 2*p + 1;
  if (q < nchA) { tile = p;     c = q; }
  else          { tile = 7 - p; c = q - nchA; }
}

__global__ __launch_bounds__(256, 4) void causal_conv_sk(
    const float* __restrict__ u, const float* __restrict__ Kt,
    float* __restrict__ y) {
  __shared__ float us[HT][USTR];   // 8448 B
  __shared__ float Kw[HT][KSTR];   // 24832 B
  int b  = blockIdx.z;
  int h0 = blockIdx.y * HT;
  int gx = (int)blockIdx.x;
  int p  = gx >> 2;
  int q0 = (gx & 3) * 4;
  int tid = (int)threadIdx.x;
  int tx = tid & 15;
  int ty = tid >> 4;

  int us_s0 = tid >> 2, us_hq = (tid & 3) * 4;
  int us_s1 = us_s0 + 64;
  const float* Krow  = &Kt[(size_t)(h0 + ty) * L_];
  const float* ubase = &u[(size_t)b * L_ * H_];

  float acc[JT];
  #pragma unroll
  for (int j = 0; j < JT; ++j) acc[j] = 0.f;

  float4 ustg0, ustg1, kstg[6];

  int cur_tile, c;
  qmap(p, q0, cur_tile, c);
  {
    int s0 = c * SC, d0 = cur_tile * TT - s0;
    ustg0 = *(const float4*)&ubase[(size_t)(s0 + us_s0)*H_ + h0 + us_hq];
    ustg1 = *(const float4*)&ubase[(size_t)(s0 + us_s1)*H_ + h0 + us_hq];
    #pragma unroll
    for (int it = 0; it < 6; ++it) {
      int kidx = d0 - 128 + 4*(tx + 16*it);
      kstg[it] = (kidx >= 0) ? *(const float4*)&Krow[kidx]
                             : make_float4(0.f,0.f,0.f,0.f);
    }
  }

  for (int i = 0; i < 4; ++i) {
    if (i) __syncthreads();
    us[us_hq+0][us_s0] = ustg0.x; us[us_hq+1][us_s0] = ustg0.y;
    us[us_hq+2][us_s0] = ustg0.z; us[us_hq+3][us_s0] = ustg0.w;
    us[us_hq+0][us_s1] = ustg1.x; us[us_hq+1][us_s1] = ustg1.y;
    us[us_hq+2][us_s1] = ustg1.z; us[us_hq+3][us_s1] = ustg1.w;
    #pragma unroll
    for (int it = 0; it < 6; ++it)
      *(float4*)&Kw[ty][4*(tx + 16*it)] = kstg[it];
    int nxt_tile = -1;
    if (i < 3) {
      int c2; qmap(p, q0 + i + 1, nxt_tile, c2);
      int s0n = c2 * SC, d0n = nxt_tile * TT - s0n;
      ustg0 = *(const float4*)&ubase[(size_t)(s0n + us_s0)*H_ + h0 + us_hq];
      ustg1 = *(const float4*)&ubase[(size_t)(s0n + us_s1)*H_ + h0 + us_hq];
      #pragma unroll
      for (int it = 0; it < 6; ++it) {
        int kidx = d0n - 128 + 4*(tx + 16*it);
        kstg[it] = (kidx >= 0) ? *(const float4*)&Krow[kidx]
                               : make_float4(0.f,0.f,0.f,0.f);
      }
    }
    __syncthreads();
    const float* usrow = &us[tx][0];
    const float* kwrow = &Kw[tx][0];
    #pragma unroll
    for (int ss = 0; ss < 8; ++ss) {
      float uu[16];
      #pragma unroll
      for (int qq = 0; qq < 4; ++qq)
        *(float4*)&uu[4*qq] = *(const float4*)&usrow[16*ss + 4*qq];
      int Wa = 112 + 16*ty - 16*ss;            // 16-aligned, in [0,352]
      float kv[32];
      #pragma unroll
      for (int qq = 0; qq < 8; ++qq)
        *(float4*)&kv[4*qq] = *(const float4*)&kwrow[Wa + 4*qq];
      #pragma unroll
      for (int j = 0; j < JT; ++j) {
        #pragma unroll
        for (int kk = 0; kk < 16; ++kk)
          acc[j] = fmaf(kv[16 + j - kk], uu[kk], acc[j]);  // d-col = Wa+16+j-kk
      }
    }
    if (nxt_tile != cur_tile) {
      int T0 = cur_tile * TT + ty * JT;
      #pragma unroll
      for (int j = 0; j < JT; ++j)
        atomicAdd(&y[((size_t)b*L_ + T0 + j)*H_ + h0 + tx], acc[j]);
      #pragma unroll
      for (int j = 0; j < JT; ++j) acc[j] = 0.f;
      cur_tile = nxt_tile;
    }
  }
}

// ---------------------------------------------------------------------------
// Kernel D: y += D * u
// ---------------------------------------------------------------------------
__global__ __launch_bounds__(256) void add_du(
    const float* __restrict__ u, const float* __restrict__ D,
    float* __restrict__ y) {
  size_t i4 = ((size_t)blockIdx.x * 256 + threadIdx.x) * 4;
  float4 uv = *(const float4*)&u[i4];
  float4 yv = *(const float4*)&y[i4];
  int hh = (int)(i4 & (H_ - 1));
  float4 dv = *(const float4*)&D[hh];
  yv.x = fmaf(dv.x, uv.x, yv.x);
  yv.y = fmaf(dv.y, uv.y, yv.y);
  yv.z = fmaf(dv.z, uv.z, yv.z);
  yv.w = fmaf(dv.w, uv.w, yv.w);
  *(float4*)&y[i4] = yv;
}

// ---------------------------------------------------------------------------
extern "C" void kernel_launch(void* const* d_in, const int* in_sizes, int n_in,
                              void* d_out, int out_size, void* d_ws, size_t ws_size,
                              hipStream_t stream) {
  const float* u        = (const float*)d_in[0];
  const float* p_ri     = (const float*)d_in[1];
  const float* q_ri     = (const float*)d_in[2];
  const float* lam_ri   = (const float*)d_in[3];
  const float* B_ri     = (const float*)d_in[4];
  const float* Ct_ri    = (const float*)d_in[5];
  const float* D        = (const float*)d_in[6];
  const float* log_step = (const float*)d_in[7];
  float* y = (float*)d_out;

  char* ws = (char*)d_ws;
  float2* at   = (float2*)ws;                                  // 4 MB
  float*  Kt   = (float*)(ws + (size_t)H_*L_*sizeof(float2));  // 2 MB
  float*  Wpre = (float*)(ws + (size_t)H_*L_*sizeof(float2)
                             + (size_t)H_*L_*sizeof(float));   // 768 KB

  (void)in_sizes; (void)n_in; (void)out_size; (void)ws_size;

  hipMemsetAsync(y, 0, (size_t)B_*L_*H_*sizeof(float), stream);
  wpre_k<<<dim3(H_*N_/256), dim3(256), 0, stream>>>(
      p_ri, q_ri, lam_ri, B_ri, Ct_ri, Wpre);
  cauchy_at_roots<<<dim3(H_*L_/256), dim3(256), 0, stream>>>(
      Wpre, log_step, at);
  fft_k<<<dim3(H_), dim3(512), 0, stream>>>(at, Kt);
  causal_conv_sk<<<dim3(16, H_/HT, B_), dim3(256), 0, stream>>>(u, Kt, y);
  add_du<<<dim3((B_*L_*H_/4)/256), dim3(256), 0, stream>>>(u, D, y);
}

// Round 10
// 176.007 us; speedup vs baseline: 1.1347x; 1.1347x over previous
//
#include <hip/hip_runtime.h>
#include <hip/hip_bf16.h>

#define H_ 256
#define N_ 64
#define L_ 2048
#define B_ 4
#define PI_ 3.14159265358979323846

// ---------------------------------------------------------------------------
// Kernel K: fused wpre + cauchy + FFT. One block (1024 thr) per h.
//   at[l] = c * (k00 - k01*k10/(1+k11)),  g = -i*(2/step)*tan(pi*l/L),
//   c = 1 - i*tan(pi*l/L);  K[t] = Re(FFT_2048(at)[t]) / 2048.
// at never touches global: written bit-reversed into FFT LDS directly.
// ---------------------------------------------------------------------------
#define SW(x) ((x) + ((x) >> 5))
__global__ __launch_bounds__(1024) void s4_kernel_K(
    const float* __restrict__ p_ri, const float* __restrict__ q_ri,
    const float* __restrict__ lam_ri, const float* __restrict__ B_ri,
    const float* __restrict__ Ct_ri, const float* __restrict__ log_step,
    float* __restrict__ K) {
  __shared__ float  wsh[N_][12];             // 3 KB: w00,w01,w10,w11,li,lr2,-lr
  __shared__ float2 data[L_ + L_/32];        // 16.9 KB
  __shared__ float2 wtab[L_/2 + L_/64];      // 8.4 KB
  int h = blockIdx.x;
  int tid = threadIdx.x;

  if (tid < N_) {
    int n = tid;
    float br  = B_ri[(h*N_+n)*2+0],  bi  = B_ri[(h*N_+n)*2+1];
    float ctr = Ct_ri[(h*N_+n)*2+0], cti = Ct_ri[(h*N_+n)*2+1];
    float pr  = p_ri[2*n+0],  pim = p_ri[2*n+1];
    float qr  = q_ri[2*n+0],  qim = q_ri[2*n+1];
    float lr  = lam_ri[2*n+0], li = lam_ri[2*n+1];
    float a0r = ctr, a0i = -cti;             // conj(Ct)
    float a1r = qr,  a1i = -qim;             // conj(q)
    wsh[n][0]  = a0r*br - a0i*bi;   wsh[n][1]  = a0r*bi + a0i*br;
    wsh[n][2]  = a0r*pr - a0i*pim;  wsh[n][3]  = a0r*pim + a0i*pr;
    wsh[n][4]  = a1r*br - a1i*bi;   wsh[n][5]  = a1r*bi + a1i*br;
    wsh[n][6]  = a1r*pr - a1i*pim;  wsh[n][7]  = a1r*pim + a1i*pr;
    wsh[n][8]  = li;  wsh[n][9] = lr*lr;  wsh[n][10] = -lr;  wsh[n][11] = 0.f;
  }
  {
    int i = tid;            // 1024 twiddles, one per thread
    float s, c;
    sincosf(-(float)(PI_ / 1024.0) * (float)i, &s, &c);
    wtab[SW(i)] = make_float2(c, s);
  }
  __syncthreads();

  float step = expf(log_step[h]);
  float tos  = 2.0f / step;
  #pragma unroll
  for (int r = 0; r < 2; ++r) {
    int l = tid + (r << 10);
    float tn = tanf((float)(PI_ / (double)L_) * (float)l);
    float G  = tos * tn;                     // g = -i*G
    float ci = -tn;                          // c = 1 - i*tn
    float k00r=0.f,k00i=0.f,k01r=0.f,k01i=0.f,k10r=0.f,k10i=0.f,k11r=0.f,k11i=0.f;
    #pragma unroll 4
    for (int n = 0; n < N_; ++n) {
      const float4* wr_ = (const float4*)&wsh[n][0];
      float4 w0 = wr_[0];                    // broadcast reads (uniform addr)
      float4 w1 = wr_[1];
      float4 cc = wr_[2];
      float ddi = -G - cc.x;
      float den = fmaf(ddi, ddi, cc.y);
      float id  = __builtin_amdgcn_rcpf(den);
      float rr  = cc.z * id;
      float ri  = -ddi * id;
      k00r = fmaf(w0.x, rr, fmaf(-w0.y, ri, k00r));
      k00i = fmaf(w0.x, ri, fmaf( w0.y, rr, k00i));
      k01r = fmaf(w0.z, rr, fmaf(-w0.w, ri, k01r));
      k01i = fmaf(w0.z, ri, fmaf( w0.w, rr, k01i));
      k10r = fmaf(w1.x, rr, fmaf(-w1.y, ri, k10r));
      k10i = fmaf(w1.x, ri, fmaf( w1.y, rr, k10i));
      k11r = fmaf(w1.z, rr, fmaf(-w1.w, ri, k11r));
      k11i = fmaf(w1.z, ri, fmaf( w1.w, rr, k11i));
    }
    float e1r = 1.0f + k11r, e1i = k11i;
    float ide = __builtin_amdgcn_rcpf(fmaf(e1r, e1r, e1i*e1i));
    float qr_ = k01r*k10r - k01i*k10i;
    float qi_ = k01r*k10i + k01i*k10r;
    float sr  = (qr_*e1r + qi_*e1i) * ide;
    float si  = (qi_*e1r - qr_*e1i) * ide;
    float fr  = k00r - sr, fi = k00i - si;
    unsigned rev = __brev((unsigned)l) >> 21;
    data[SW(rev)] = make_float2(fr - ci*fi, fi + ci*fr);
  }
  __syncthreads();

  for (int m = 2; m <= L_; m <<= 1) {
    int half = m >> 1;
    int tstep = L_ / m;
    int bfly = tid;                          // exactly 1024 butterflies
    int pos = bfly & (half - 1);
    int i0  = ((bfly ^ pos) << 1) + pos;
    float2 w = wtab[SW(pos * tstep)];
    float2 a = data[SW(i0)];
    float2 b = data[SW(i0 + half)];
    float trr = w.x*b.x - w.y*b.y;
    float tii = w.x*b.y + w.y*b.x;
    data[SW(i0)]        = make_float2(a.x + trr, a.y + tii);
    data[SW(i0 + half)] = make_float2(a.x - trr, a.y - tii);
    __syncthreads();
  }
  #pragma unroll
  for (int r = 0; r < 2; ++r) {
    int i = tid + (r << 10);
    K[h*L_ + i] = data[SW(i)].x * (1.0f / (float)L_);
  }
}

// ---------------------------------------------------------------------------
// Kernel C: split-K causal conv, CORRECT chunk coverage: tile p gets 2p+2
// chunks (last chunk d0=-128 zero-padded for s>t). Pair (p,7-p) = 18 chunks
// -> 3 blocks x 6 chunks -> grid 12x16x4 = 768 uniform blocks = 3/CU.
// S=8 inner loop (round-8 proven, no spill). D*u fused into the d0==0 /
// d0==-128 chunks (lo/hi output halves) from the us[] LDS tile.
// ---------------------------------------------------------------------------
#define HT 16
#define TT 256
#define SC 128
#define JT 16
#define USTR 132
#define KSTR 388

__device__ __forceinline__ void qmap18(int p, int q, int& tile, int& c) {
  int nchA = 2*p + 2;                 // chunks in tile p (incl. d0=-128)
  if (q < nchA) { tile = p;     c = q; }
  else          { tile = 7 - p; c = q - nchA; }
}

__global__ __launch_bounds__(256, 4) void causal_conv_sk(
    const float* __restrict__ u, const float* __restrict__ Kt,
    const float* __restrict__ D, float* __restrict__ y) {
  __shared__ float us[HT][USTR];   // 8448 B
  __shared__ float Kw[HT][KSTR];   // 24832 B
  int b  = blockIdx.z;
  int h0 = blockIdx.y * HT;
  int gx = (int)blockIdx.x;        // 0..11
  int p  = gx / 3;                 // pair index 0..3
  int q0 = (gx % 3) * 6;           // first chunk slot
  int tid = (int)threadIdx.x;
  int tx = tid & 15;
  int ty = tid >> 4;

  int us_s0 = tid >> 2, us_hq = (tid & 3) * 4;
  int us_s1 = us_s0 + 64;
  const float* Krow  = &Kt[(size_t)(h0 + ty) * L_];
  const float* ubase = &u[(size_t)b * L_ * H_];
  float Dh = D[h0 + tx];

  float acc[JT];
  #pragma unroll
  for (int j = 0; j < JT; ++j) acc[j] = 0.f;

  float4 ustg0, ustg1, kstg[6];

  int cur_tile, cur_c;
  qmap18(p, q0, cur_tile, cur_c);
  int cur_d0 = cur_tile * TT - cur_c * SC;
  {
    int s0 = cur_c * SC;
    ustg0 = *(const float4*)&ubase[(size_t)(s0 + us_s0)*H_ + h0 + us_hq];
    ustg1 = *(const float4*)&ubase[(size_t)(s0 + us_s1)*H_ + h0 + us_hq];
    #pragma unroll
    for (int it = 0; it < 6; ++it) {
      int kidx = cur_d0 - 128 + 4*(tx + 16*it);
      kstg[it] = (kidx >= 0) ? *(const float4*)&Krow[kidx]
                             : make_float4(0.f,0.f,0.f,0.f);
    }
  }

  for (int i = 0; i < 6; ++i) {
    if (i) __syncthreads();
    us[us_hq+0][us_s0] = ustg0.x; us[us_hq+1][us_s0] = ustg0.y;
    us[us_hq+2][us_s0] = ustg0.z; us[us_hq+3][us_s0] = ustg0.w;
    us[us_hq+0][us_s1] = ustg1.x; us[us_hq+1][us_s1] = ustg1.y;
    us[us_hq+2][us_s1] = ustg1.z; us[us_hq+3][us_s1] = ustg1.w;
    #pragma unroll
    for (int it = 0; it < 6; ++it)
      *(float4*)&Kw[ty][4*(tx + 16*it)] = kstg[it];
    int nxt_tile = -1, nxt_c = 0;
    if (i < 5) {
      qmap18(p, q0 + i + 1, nxt_tile, nxt_c);
      int s0n = nxt_c * SC, d0n = nxt_tile * TT - s0n;
      ustg0 = *(const float4*)&ubase[(size_t)(s0n + us_s0)*H_ + h0 + us_hq];
      ustg1 = *(const float4*)&ubase[(size_t)(s0n + us_s1)*H_ + h0 + us_hq];
      #pragma unroll
      for (int it = 0; it < 6; ++it) {
        int kidx = d0n - 128 + 4*(tx + 16*it);
        kstg[it] = (kidx >= 0) ? *(const float4*)&Krow[kidx]
                               : make_float4(0.f,0.f,0.f,0.f);
      }
    }
    __syncthreads();
    const float* usrow = &us[tx][0];
    const float* kwrow = &Kw[tx][0];
    #pragma unroll 2
    for (int ss = 0; ss < 16; ++ss) {
      float4 ua = *(const float4*)&usrow[8*ss];
      float4 ub = *(const float4*)&usrow[8*ss + 4];
      int Wb = 120 + JT*ty - 8*ss;
      float kv[24];
      #pragma unroll
      for (int qq = 0; qq < 6; ++qq)
        *(float4*)&kv[4*qq] = *(const float4*)&kwrow[Wb + 4*qq];
      float uu[8] = {ua.x, ua.y, ua.z, ua.w, ub.x, ub.y, ub.z, ub.w};
      #pragma unroll
      for (int j = 0; j < JT; ++j) {
        #pragma unroll
        for (int kk = 0; kk < 8; ++kk)
          acc[j] = fmaf(kv[8 + j - kk], uu[kk], acc[j]);
      }
    }
    // fused D*u: diagonal chunk (d0==0) serves lo-half outputs, the
    // d0==-128 chunk serves hi-half (its us holds s in [t0+128,t0+256)).
    if (cur_d0 == 0 && ty < 8) {
      #pragma unroll
      for (int j = 0; j < JT; ++j)
        acc[j] = fmaf(Dh, usrow[16*ty + j], acc[j]);
    } else if (cur_d0 == -SC && ty >= 8) {
      #pragma unroll
      for (int j = 0; j < JT; ++j)
        acc[j] = fmaf(Dh, usrow[16*ty + j - 128], acc[j]);
    }
    if (nxt_tile != cur_tile) {
      int T0 = cur_tile * TT + ty * JT;
      #pragma unroll
      for (int j = 0; j < JT; ++j)
        atomicAdd(&y[((size_t)b*L_ + T0 + j)*H_ + h0 + tx], acc[j]);
      #pragma unroll
      for (int j = 0; j < JT; ++j) acc[j] = 0.f;
    }
    cur_tile = nxt_tile; cur_c = nxt_c;
    cur_d0 = cur_tile * TT - cur_c * SC;
  }
}

// ---------------------------------------------------------------------------
extern "C" void kernel_launch(void* const* d_in, const int* in_sizes, int n_in,
                              void* d_out, int out_size, void* d_ws, size_t ws_size,
                              hipStream_t stream) {
  const float* u        = (const float*)d_in[0];
  const float* p_ri     = (const float*)d_in[1];
  const float* q_ri     = (const float*)d_in[2];
  const float* lam_ri   = (const float*)d_in[3];
  const float* B_ri     = (const float*)d_in[4];
  const float* Ct_ri    = (const float*)d_in[5];
  const float* D        = (const float*)d_in[6];
  const float* log_step = (const float*)d_in[7];
  float* y = (float*)d_out;

  float* Kt = (float*)d_ws;                 // H*L f32 = 2 MB

  (void)in_sizes; (void)n_in; (void)out_size; (void)ws_size;

  hipMemsetAsync(y, 0, (size_t)B_*L_*H_*sizeof(float), stream);
  s4_kernel_K<<<dim3(H_), dim3(1024), 0, stream>>>(
      p_ri, q_ri, lam_ri, B_ri, Ct_ri, log_step, Kt);
  causal_conv_sk<<<dim3(12, H_/HT, B_), dim3(256), 0, stream>>>(u, Kt, D, y);
}

// Round 13
// 129.574 us; speedup vs baseline: 1.5414x; 1.3584x over previous
//
#include <hip/hip_runtime.h>
#include <hip/hip_bf16.h>
#include <stdint.h>

#define H_ 256
#define N_ 64
#define L_ 2048
#define B_ 4
#define PI_ 3.14159265358979323846

typedef short short8 __attribute__((ext_vector_type(8)));
typedef float f32x4 __attribute__((ext_vector_type(4)));

__device__ __forceinline__ uint32_t rne_bf16(float x) {
  uint32_t u = __float_as_uint(x);
  return (u + 0x7FFFu + ((u >> 16) & 1u)) >> 16;
}

// ---------------------------------------------------------------------------
// Kernel A0: per-(h,n) weight products -> Wpre[h*64+n] = 12 floats
// ---------------------------------------------------------------------------
__global__ __launch_bounds__(256) void wpre_k(
    const float* __restrict__ p_ri, const float* __restrict__ q_ri,
    const float* __restrict__ lam_ri, const float* __restrict__ B_ri,
    const float* __restrict__ Ct_ri, float* __restrict__ Wpre) {
  int idx = blockIdx.x * 256 + threadIdx.x;
  int h = idx >> 6, n = idx & 63;
  float br  = B_ri[(h*N_+n)*2+0],  bi  = B_ri[(h*N_+n)*2+1];
  float ctr = Ct_ri[(h*N_+n)*2+0], cti = Ct_ri[(h*N_+n)*2+1];
  float pr  = p_ri[2*n+0],  pim = p_ri[2*n+1];
  float qr  = q_ri[2*n+0],  qim = q_ri[2*n+1];
  float lr  = lam_ri[2*n+0], li = lam_ri[2*n+1];
  float a0r = ctr, a0i = -cti;
  float a1r = qr,  a1i = -qim;
  float4* wp = (float4*)(Wpre + (size_t)idx * 12);
  wp[0] = make_float4(a0r*br - a0i*bi,  a0r*bi + a0i*br,
                      a0r*pr - a0i*pim, a0r*pim + a0i*pr);
  wp[1] = make_float4(a1r*br - a1i*bi,  a1r*bi + a1i*br,
                      a1r*pr - a1i*pim, a1r*pim + a1i*pr);
  wp[2] = make_float4(li, lr*lr, -lr, 0.f);
}

// ---------------------------------------------------------------------------
// Kernel A: at_roots[h][l] (f32, zero LDS; Wpre reads are block-uniform)
// ---------------------------------------------------------------------------
__global__ __launch_bounds__(256) void cauchy_at_roots(
    const float* __restrict__ Wpre, const float* __restrict__ log_step,
    float2* __restrict__ at) {
  int h = blockIdx.x >> 3;
  int l = ((blockIdx.x & 7) << 8) | threadIdx.x;

  float step = expf(log_step[h]);
  float tn   = tanf((float)(PI_ / (double)L_) * (float)l);
  float G    = (2.0f / step) * tn;
  float ci   = -tn;

  const float4* __restrict__ wp = (const float4*)(Wpre + (size_t)h * N_ * 12);

  float k00r=0.f,k00i=0.f,k01r=0.f,k01i=0.f,k10r=0.f,k10i=0.f,k11r=0.f,k11i=0.f;
  #pragma unroll 4
  for (int n = 0; n < N_; ++n) {
    float4 w0 = wp[3*n+0];
    float4 w1 = wp[3*n+1];
    float4 cc = wp[3*n+2];
    float ddi = -G - cc.x;
    float den = fmaf(ddi, ddi, cc.y);
    float id  = __builtin_amdgcn_rcpf(den);
    float rr  = cc.z * id;
    float ri  = -ddi * id;
    k00r = fmaf(w0.x, rr, fmaf(-w0.y, ri, k00r));
    k00i = fmaf(w0.x, ri, fmaf( w0.y, rr, k00i));
    k01r = fmaf(w0.z, rr, fmaf(-w0.w, ri, k01r));
    k01i = fmaf(w0.z, ri, fmaf( w0.w, rr, k01i));
    k10r = fmaf(w1.x, rr, fmaf(-w1.y, ri, k10r));
    k10i = fmaf(w1.x, ri, fmaf( w1.y, rr, k10i));
    k11r = fmaf(w1.z, rr, fmaf(-w1.w, ri, k11r));
    k11i = fmaf(w1.z, ri, fmaf( w1.w, rr, k11i));
  }
  float e1r = 1.0f + k11r, e1i = k11i;
  float ide = __builtin_amdgcn_rcpf(fmaf(e1r, e1r, e1i*e1i));
  float qr_ = k01r*k10r - k01i*k10i;
  float qi_ = k01r*k10i + k01i*k10r;
  float sr  = (qr_*e1r + qi_*e1i) * ide;
  float si  = (qi_*e1r - qr_*e1i) * ide;
  float fr  = k00r - sr, fi = k00i - si;
  at[h*L_ + l] = make_float2(fr - ci*fi, fi + ci*fr);
}

// ---------------------------------------------------------------------------
// Kernel B: K[h,t] = Re(FFT_2048(at[h,:])[t]) / 2048  (1024 thr, LDS swizzled)
// ---------------------------------------------------------------------------
#define SW(x) ((x) + ((x) >> 5))
__global__ __launch_bounds__(1024) void fft_k(
    const float2* __restrict__ at, float* __restrict__ K) {
  __shared__ float2 data[L_ + L_/32];
  __shared__ float2 wtab[L_/2 + L_/64];
  int h = blockIdx.x;
  int tid = threadIdx.x;

  {
    float s, c;
    sincosf(-(float)(PI_ / 1024.0) * (float)tid, &s, &c);
    wtab[SW(tid)] = make_float2(c, s);
  }
  #pragma unroll
  for (int r = 0; r < 2; ++r) {
    int i = tid + (r << 10);
    unsigned rev = __brev((unsigned)i) >> 21;
    data[SW(rev)] = at[h*L_ + i];
  }
  __syncthreads();

  for (int m = 2; m <= L_; m <<= 1) {
    int half = m >> 1;
    int tstep = L_ / m;
    int pos = tid & (half - 1);
    int i0  = ((tid ^ pos) << 1) + pos;
    float2 w = wtab[SW(pos * tstep)];
    float2 a = data[SW(i0)];
    float2 b = data[SW(i0 + half)];
    float trr = w.x*b.x - w.y*b.y;
    float tii = w.x*b.y + w.y*b.x;
    data[SW(i0)]        = make_float2(a.x + trr, a.y + tii);
    data[SW(i0 + half)] = make_float2(a.x - trr, a.y - tii);
    __syncthreads();
  }
  #pragma unroll
  for (int r = 0; r < 2; ++r) {
    int i = tid + (r << 10);
    K[h*L_ + i] = data[SW(i)].x * (1.0f / (float)L_);
  }
}

// ---------------------------------------------------------------------------
// Kernel C: MFMA causal conv. One block (512 thr, 8 waves) per h.
// D[i,j] = sum_k A[i,k]*B[k,j]; A[i,k]=K[delta+i-k] (Toeplitz, bf16, from
// reversed-K LDS with even/odd phase copies); B[k,j]=u[b_j, S0b+32*m_j+k]
// (bf16 LDS, 96-elem zero head). j = 4b x 4m (diag translates, spacing 32).
// Output tiles: t = 128g + 16*tau + 32m + i; wave w owns g in {w, 15-w},
// both tau fused (shared B-frag + shared A word-pair). Acc in f32; epilogue
// adds D*u (f32) and writes y directly (no atomics, no memset).
// A/B fragment layout (16x16x32): lane l -> row/col = l&15,
// k = 16*(e>>2) + 4*(l>>4) + (e&3), e = 0..7.  C/D: col=l&15, row=4*(l>>4)+r.
// ---------------------------------------------------------------------------
__global__ __launch_bounds__(512) void conv_mfma(
    const float* __restrict__ u, const float* __restrict__ Kt,
    const float* __restrict__ D, float* __restrict__ y) {
  __shared__ unsigned short ubf[B_][2192];   // 96 zero-head + 2048 + pad
  __shared__ uint32_t kre[1060];             // (KR[2w],KR[2w+1]), KR[x]=K[2047-x]
  __shared__ uint32_t kro[1060];             // (KR[2w+1],KR[2w+2]); zeros x>2047
  int h = ((int)(blockIdx.x & 7) << 5) | ((int)blockIdx.x >> 3);  // XCD swizzle
  int tid = (int)threadIdx.x;

  // ---- stage u (f32 global, strided) -> bf16 LDS ----
  const float* ugh = u + h;
  for (int x = tid; x < 4096; x += 512) {
    int bb = x >> 10, sp = x & 1023;
    float v0 = ugh[(size_t)(bb * L_ + 2 * sp) * H_];
    float v1 = ugh[(size_t)(bb * L_ + 2 * sp + 1) * H_];
    ((uint32_t*)&ubf[bb][96])[sp] = rne_bf16(v0) | (rne_bf16(v1) << 16);
  }
  if (tid < 192) {                       // zero the 96-elem heads
    int bb = tid / 48, wd = tid % 48;
    ((uint32_t*)&ubf[bb][0])[wd] = 0u;
  }
  // ---- stage K reversed bf16, two phase copies ----
  const float* Kh = Kt + (size_t)h * L_;
  for (int wd = tid; wd < 1060; wd += 512) {
    int d0 = 2047 - 2 * wd;
    uint32_t e0 = (d0 >= 0) ? rne_bf16(Kh[d0])     : 0u;
    uint32_t e1 = (d0 >= 1) ? rne_bf16(Kh[d0 - 1]) : 0u;
    uint32_t e2 = (d0 >= 2) ? rne_bf16(Kh[d0 - 2]) : 0u;
    kre[wd] = e0 | (e1 << 16);
    kro[wd] = e1 | (e2 << 16);
  }
  __syncthreads();

  int lane = tid & 63;
  int wv   = tid >> 6;                   // 0..7
  int i_   = lane & 15;                  // A row / B,D col
  int q_   = lane >> 4;                  // 0..3
  int bj   = i_ >> 2;                    // batch of this D-column
  int mj   = i_ & 3;                     // diag-translate of this D-column
  float Dh = D[h];

  #pragma unroll
  for (int halfsel = 0; halfsel < 2; ++halfsel) {
    int gg = halfsel ? (15 - wv) : wv;
    // A base: x0(tau0,start) = 1951 - 128g - i + 4q ; tau1 at -16 (word -8)
    int X0 = 1951 - 128 * gg - i_ + 4 * q_;
    const uint32_t* KA = (X0 & 1) ? kro : kre;
    int w0 = X0 >> 1;
    const unsigned short* ub = &ubf[bj][32 * mj + 4 * q_];
    f32x4 acc0 = {0.f, 0.f, 0.f, 0.f};
    f32x4 acc1 = {0.f, 0.f, 0.f, 0.f};
    for (int s4 = 0; s4 <= gg; ++s4) {
      #pragma unroll
      for (int uu = 0; uu < 4; ++uu) {
        union { uint32_t w[4]; short8 v; } A0, A1, Bv;
        uint32_t c0 = KA[w0 + 0], c1 = KA[w0 + 1];     // shared words
        A0.w[0] = c0;           A0.w[1] = c1;
        A0.w[2] = KA[w0 + 8];   A0.w[3] = KA[w0 + 9];
        A1.w[0] = KA[w0 - 8];   A1.w[1] = KA[w0 - 7];
        A1.w[2] = c0;           A1.w[3] = c1;
        Bv.w[0] = *(const uint32_t*)(ub + 0);
        Bv.w[1] = *(const uint32_t*)(ub + 2);
        Bv.w[2] = *(const uint32_t*)(ub + 16);
        Bv.w[3] = *(const uint32_t*)(ub + 18);
        acc0 = __builtin_amdgcn_mfma_f32_16x16x32_bf16(A0.v, Bv.v, acc0, 0, 0, 0);
        acc1 = __builtin_amdgcn_mfma_f32_16x16x32_bf16(A1.v, Bv.v, acc1, 0, 0, 0);
        w0 += 16; ub += 32;
      }
    }
    // ---- epilogue: y = conv + D*u (f32), direct write ----
    int tb = 128 * gg + 32 * mj + 4 * q_;
    #pragma unroll
    for (int r = 0; r < 4; ++r) {
      size_t o0 = ((size_t)(bj * L_ + tb + r)) * H_ + h;
      y[o0] = acc0[r] + Dh * u[o0];
      size_t o1 = o0 + (size_t)16 * H_;      // tau=1 tile: t + 16
      y[o1] = acc1[r] + Dh * u[o1];
    }
  }
}

// ---------------------------------------------------------------------------
extern "C" void kernel_launch(void* const* d_in, const int* in_sizes, int n_in,
                              void* d_out, int out_size, void* d_ws, size_t ws_size,
                              hipStream_t stream) {
  const float* u        = (const float*)d_in[0];
  const float* p_ri     = (const float*)d_in[1];
  const float* q_ri     = (const float*)d_in[2];
  const float* lam_ri   = (const float*)d_in[3];
  const float* B_ri     = (const float*)d_in[4];
  const float* Ct_ri    = (const float*)d_in[5];
  const float* D        = (const float*)d_in[6];
  const float* log_step = (const float*)d_in[7];
  float* y = (float*)d_out;

  char* ws = (char*)d_ws;
  float2* at   = (float2*)ws;                                  // 4 MB
  float*  Kt   = (float*)(ws + (size_t)H_*L_*sizeof(float2));  // 2 MB
  float*  Wpre = (float*)(ws + (size_t)H_*L_*sizeof(float2)
                             + (size_t)H_*L_*sizeof(float));   // 768 KB

  (void)in_sizes; (void)n_in; (void)out_size; (void)ws_size;

  wpre_k<<<dim3(H_*N_/256), dim3(256), 0, stream>>>(
      p_ri, q_ri, lam_ri, B_ri, Ct_ri, Wpre);
  cauchy_at_roots<<<dim3(H_*L_/256), dim3(256), 0, stream>>>(
      Wpre, log_step, at);
  fft_k<<<dim3(H_), dim3(1024), 0, stream>>>(at, Kt);
  conv_mfma<<<dim3(H_), dim3(512), 0, stream>>>(u, Kt, D, y);
}